// Round 3
// baseline (4992.027 us; speedup 1.0000x reference)
//
#include <hip/hip_runtime.h>
#include <cstdint>
#include <cstddef>

#define Tt  512
#define Kk  8
#define NI  256
#define UN  256

typedef unsigned short ushort_t;
typedef __attribute__((ext_vector_type(8))) short short8;
typedef __attribute__((ext_vector_type(4))) float f32x4;

__global__ void zero_ws(unsigned int* p, int n) {
    int stride = gridDim.x * blockDim.x;
    for (int i = blockIdx.x * blockDim.x + threadIdx.x; i < n; i += stride)
        p[i] = 0u;
}

__device__ __forceinline__ ushort_t f2bf(float x) {
    union { float f; unsigned int u; } v; v.f = x;
    unsigned int r = v.u + 0x7FFFu + ((v.u >> 16) & 1u);
    return (ushort_t)(r >> 16);
}

__device__ __forceinline__ float hsig(float z) {
    return fminf(1.0f, fmaxf(0.0f, fmaf(z, 0.2f, 0.5f)));
}

__device__ __forceinline__ float fast_tanh(float x) {
    float e = __expf(2.0f * x);
    return 1.0f - 2.0f * __builtin_amdgcn_rcpf(e + 1.0f);
}

// ---- one-time: x fp32 -> bf16 (same layout) ----
__global__ __launch_bounds__(256) void conv_x(const float* __restrict__ x,
                                              ushort_t* __restrict__ xb, int n4) {
    int stride = gridDim.x * blockDim.x;
    for (int i = blockIdx.x * blockDim.x + threadIdx.x; i < n4; i += stride) {
        float4 v = ((const float4*)x)[i];
        ushort4 o;
        o.x = f2bf(v.x); o.y = f2bf(v.y); o.z = f2bf(v.z); o.w = f2bf(v.w);
        ((ushort4*)xb)[i] = o;
    }
}

// ---- one-time: W[k][i][col] fp32 -> Wt[k][col][i] bf16 ----
__global__ __launch_bounds__(256) void conv_wt(const float* __restrict__ W,
                                               ushort_t* __restrict__ Wt) {
    __shared__ float s[32][33];
    const int k = blockIdx.z, ct = blockIdx.x * 32, it = blockIdx.y * 32;
    const int tx = threadIdx.x & 31, ty = threadIdx.x >> 5;  // ty 0..7
#pragma unroll
    for (int r = 0; r < 4; r++)
        s[ty * 4 + r][tx] = W[((size_t)k * NI + it + ty * 4 + r) * 1024 + ct + tx];
    __syncthreads();
#pragma unroll
    for (int r = 0; r < 4; r++)
        Wt[((size_t)k * 1024 + ct + ty * 4 + r) * NI + it + tx] = f2bf(s[tx][ty * 4 + r]);
}

// ---- Phase A: xw = bias + x@W, bf16 MFMA, 128x128 tile ----
// grid (1024/128, TC*16/128, 8), block 256 (4 waves, 2x2, 64x64 each)
__global__ __launch_bounds__(256) void xw_gemm_mfma(const ushort_t* __restrict__ xb,
                                                    const ushort_t* __restrict__ Wt,
                                                    const float* __restrict__ bias,
                                                    float* __restrict__ xw, int t0) {
    __shared__ __align__(16) ushort_t As[128 * 40];  // [row][kk], stride 40 elems
    __shared__ __align__(16) ushort_t Bs[128 * 40];  // [col][kk]
    const int k = blockIdx.z, C0 = blockIdx.x * 128, R0 = blockIdx.y * 128;
    const int tid = threadIdx.x, lane = tid & 63, wave = tid >> 6;
    const int l15 = lane & 15, quad = lane >> 4;
    const int wy = wave >> 1, wx = wave & 1;

    f32x4 acc[4][4];
    const f32x4 zv = {0.f, 0.f, 0.f, 0.f};
#pragma unroll
    for (int mi = 0; mi < 4; mi++)
#pragma unroll
        for (int ni = 0; ni < 4; ni++) acc[mi][ni] = zv;

    for (int kt = 0; kt < NI; kt += 32) {
        if (kt) __syncthreads();
#pragma unroll
        for (int i = 0; i < 2; i++) {
            int c = tid + 256 * i;
            int rl = c >> 2, kc = c & 3;
            int r = R0 + rl, b = r & 15, tp = r >> 4;
            short8 av = *(const short8*)&xb[(((size_t)b * Tt + (t0 + tp)) * Kk + k) * NI + kt + kc * 8];
            *(short8*)&As[rl * 40 + kc * 8] = av;
            short8 bv = *(const short8*)&Wt[((size_t)k * 1024 + C0 + rl) * NI + kt + kc * 8];
            *(short8*)&Bs[rl * 40 + kc * 8] = bv;
        }
        __syncthreads();
        short8 af[4], bf[4];
#pragma unroll
        for (int mi = 0; mi < 4; mi++)
            af[mi] = *(const short8*)&As[(wy * 64 + mi * 16 + l15) * 40 + quad * 8];
#pragma unroll
        for (int ni = 0; ni < 4; ni++)
            bf[ni] = *(const short8*)&Bs[(wx * 64 + ni * 16 + l15) * 40 + quad * 8];
#pragma unroll
        for (int mi = 0; mi < 4; mi++)
#pragma unroll
            for (int ni = 0; ni < 4; ni++)
                acc[mi][ni] = __builtin_amdgcn_mfma_f32_16x16x32_bf16(af[mi], bf[ni], acc[mi][ni], 0, 0, 0);
    }
#pragma unroll
    for (int ni = 0; ni < 4; ni++) {
        float bv = bias[(size_t)k * 1024 + C0 + wx * 64 + ni * 16 + l15];
#pragma unroll
        for (int mi = 0; mi < 4; mi++)
#pragma unroll
            for (int reg = 0; reg < 4; reg++) {
                int r = R0 + wy * 64 + mi * 16 + quad * 4 + reg;
                int b = r & 15, tp = r >> 4;
                xw[((size_t)tp * 128 + b * 8 + k) * 1024 + C0 + wx * 64 + ni * 16 + l15]
                    = acc[mi][ni][reg] + bv;
            }
    }
}

// ---- Phase B: 16 wgs x 512 thr. k=bid&7, uq=bid>>3 owns units [uq*128,uq*128+128).
// wave w: gate g8=w>>1, half sh=w&1 -> 64 cols; B-frags 128 VGPR/lane.
__global__ __launch_bounds__(512, 2) void lstm_mfma2(
    const float* __restrict__ xw,        // [TC][128][1024]
    const float* __restrict__ U,
    float* __restrict__ out,
    ushort_t* __restrict__ hstate,       // [8][16][256] bf16
    float* __restrict__ cstate,          // [16][2048]
    ushort_t* __restrict__ hbuf,         // [2][8][16*256] bf16
    int* __restrict__ arrive,            // [8][512]
    int t0, int TC) {
    const int tid  = threadIdx.x;
    const int lane = tid & 63;
    const int w    = tid >> 6;           // 0..7
    const int k    = blockIdx.x & 7;
    const int uq   = blockIdx.x >> 3;    // 0..1
    const int l15  = lane & 15, quad = lane >> 4;
    const int g8   = w >> 1, sh = w & 1;
    const int colw = g8 * 256 + uq * 128 + sh * 64;

    __shared__ __align__(16) ushort_t hfr[8 * 64 * 8];   // A-frag layout
    __shared__ float gact[4][16][132];

    // preload B-fragments of U slice (bf16)
    short8 bfr[4][8];
    const size_t Ub = (size_t)k * (NI * 1024);
#pragma unroll
    for (int c = 0; c < 4; c++) {
        const int col = colw + c * 16 + l15;
#pragma unroll
        for (int q = 0; q < 8; q++) {
            short8 v;
#pragma unroll
            for (int j = 0; j < 8; j++)
                v[j] = (short)f2bf(U[Ub + (size_t)(q * 32 + quad * 8 + j) * 1024 + col]);
            bfr[c][q] = v;
        }
    }

    float cc[4];
    const size_t cb = ((size_t)(k * 2 + uq)) * 2048 + (size_t)tid * 4;
#pragma unroll
    for (int r = 0; r < 4; r++) cc[r] = cstate[cb + r];

    const int su = tid & 127;   // u' within 128-unit slice
    const int sb = tid >> 7;    // batch quarter

    // initial h scatter: hstate -> A-frag LDS (1 x 16B load + 1 x b128 write per thread)
    {
        const int b = tid & 15, c8 = tid >> 4;
        short8 hv = *(const short8*)&hstate[((size_t)k * 16 + b) * 256 + c8 * 8];
        *(short8*)&hfr[(((c8 >> 2) * 64) + b + 16 * (c8 & 3)) * 8] = hv;
    }
    __syncthreads();

    float xwv[4][4];
#pragma unroll
    for (int c = 0; c < 4; c++)
#pragma unroll
        for (int r = 0; r < 4; r++)
            xwv[c][r] = xw[((size_t)0 * 128 + (quad * 4 + r) * 8 + k) * 1024 + colw + c * 16 + l15];

#pragma unroll 1
    for (int t = 0; t < TC; t++) {
        const int g = t0 + t;

        f32x4 acc[4];
        const f32x4 zv = {0.f, 0.f, 0.f, 0.f};
#pragma unroll
        for (int c = 0; c < 4; c++) acc[c] = zv;
#pragma unroll
        for (int q = 0; q < 8; q++) {
            short8 af = *(const short8*)&hfr[(q * 64 + lane) * 8];
#pragma unroll
            for (int c = 0; c < 4; c++)
                acc[c] = __builtin_amdgcn_mfma_f32_16x16x32_bf16(af, bfr[c][q], acc[c], 0, 0, 0);
        }

        float xwn[4][4];
        if (t + 1 < TC) {
#pragma unroll
            for (int c = 0; c < 4; c++)
#pragma unroll
                for (int r = 0; r < 4; r++)
                    xwn[c][r] = xw[((size_t)(t + 1) * 128 + (quad * 4 + r) * 8 + k) * 1024 + colw + c * 16 + l15];
        }

#pragma unroll
        for (int c = 0; c < 4; c++)
#pragma unroll
            for (int r = 0; r < 4; r++) {
                float z = acc[c][r] + xwv[c][r];
                float a = (g8 == 0) ? fast_tanh(z) : hsig(z);
                gact[g8][quad * 4 + r][sh * 64 + c * 16 + l15] = a;
            }
        __syncthreads();   // S1: gact visible, hfr reads done

        float hn[4];
#pragma unroll
        for (int r = 0; r < 4; r++) {
            int b = sb * 4 + r;
            float av = gact[0][b][su], iv = gact[1][b][su];
            float fv = gact[2][b][su], ov = gact[3][b][su];
            float cn = av * iv + fv * cc[r];
            cc[r] = cn;
            hn[r] = ov * fast_tanh(cn);
            out[(((size_t)b * Tt + g) * Kk + k) * UN + uq * 128 + su] = hn[r];
        }

        if (t + 1 < TC) {
            const int par = (g + 1) & 1;
            ushort_t* hb = hbuf + ((size_t)par * 8 + k) * 4096;
#pragma unroll
            for (int r = 0; r < 4; r++)
                hb[(sb * 4 + r) * 256 + uq * 128 + su] = f2bf(hn[r]);
            // per-wave release + spin (flag counts waves: 2 wgs x 8 = 16)
            if ((tid & 63) == 0) {
                int* flag = arrive + k * 512 + (g + 1);
                __hip_atomic_fetch_add(flag, 1, __ATOMIC_RELEASE, __HIP_MEMORY_SCOPE_AGENT);
                while (__hip_atomic_load(flag, __ATOMIC_ACQUIRE, __HIP_MEMORY_SCOPE_AGENT) < 16) {}
            }
            __syncthreads();   // S3: all waves saw flag==16
            {
                const int b = tid & 15, c8 = tid >> 4;
                short8 hv = *(const short8*)&hb[b * 256 + c8 * 8];
                *(short8*)&hfr[(((c8 >> 2) * 64) + b + 16 * (c8 & 3)) * 8] = hv;
            }
            __syncthreads();   // S4: hfr ready
#pragma unroll
            for (int c = 0; c < 4; c++)
#pragma unroll
                for (int r = 0; r < 4; r++) xwv[c][r] = xwn[c][r];
        } else {
#pragma unroll
            for (int r = 0; r < 4; r++)
                hstate[((size_t)k * 16 + sb * 4 + r) * 256 + uq * 128 + su] = f2bf(hn[r]);
#pragma unroll
            for (int r = 0; r < 4; r++) cstate[cb + r] = cc[r];
        }
    }
}

extern "C" void kernel_launch(void* const* d_in, const int* in_sizes, int n_in,
                              void* d_out, int out_size, void* d_ws, size_t ws_size,
                              hipStream_t stream) {
    const float* x    = (const float*)d_in[0];
    const float* W    = (const float*)d_in[1];
    const float* U    = (const float*)d_in[2];
    const float* bias = (const float*)d_in[3];
    float* out = (float*)d_out;

    const size_t XB   = (size_t)16 * 512 * 8 * 256 * 2;   // 33554432
    const size_t WTB  = (size_t)8 * 256 * 1024 * 2;       //  4194304
    const size_t TAIL = 131072 + 65536 + 131072 + 16384;  //   344064

    int TC = 16;
    const int cands[6] = {512, 256, 128, 64, 32, 16};
    for (int ci = 0; ci < 6; ci++) {
        size_t need = XB + WTB + (size_t)cands[ci] * 128 * 1024 * 4 + TAIL;
        if (need <= ws_size) { TC = cands[ci]; break; }
    }

    ushort_t* xb = (ushort_t*)d_ws;
    ushort_t* Wt = (ushort_t*)((char*)d_ws + XB);
    float*    xw = (float*)((char*)d_ws + XB + WTB);
    char* p = (char*)d_ws + XB + WTB + (size_t)TC * 128 * 1024 * 4;
    float*    cstate = (float*)p;     p += 131072;
    ushort_t* hstate = (ushort_t*)p;  p += 65536;
    ushort_t* hbuf   = (ushort_t*)p;  p += 131072;
    int*      arrive = (int*)p;

    zero_ws<<<dim3(128), dim3(256), 0, stream>>>((unsigned int*)cstate, (int)(TAIL / 4));
    conv_x<<<dim3(2048), dim3(256), 0, stream>>>(x, xb, 16 * 512 * 8 * 256 / 4);
    conv_wt<<<dim3(32, 8, 8), dim3(256), 0, stream>>>(W, Wt);

    for (int t0 = 0; t0 < Tt; t0 += TC) {
        xw_gemm_mfma<<<dim3(8, TC * 16 / 128, Kk), dim3(256), 0, stream>>>(
            xb, Wt, bias, xw, t0);
        lstm_mfma2<<<dim3(16), dim3(512), 0, stream>>>(
            xw, U, out, hstate, cstate, hbuf, arrive, t0, TC);
    }
}

// Round 4
// 2569.267 us; speedup vs baseline: 1.9430x; 1.9430x over previous
//
#include <hip/hip_runtime.h>
#include <cstdint>
#include <cstddef>

#define Tt  512
#define Kk  8
#define NI  256
#define UN  256
#define G4  1024   // 4*UN

typedef unsigned short ushort_t;
typedef __attribute__((ext_vector_type(8))) short short8;
typedef __attribute__((ext_vector_type(4))) float f32x4;

__global__ void zero_ws(unsigned int* p, int n) {
    int stride = gridDim.x * blockDim.x;
    for (int i = blockIdx.x * blockDim.x + threadIdx.x; i < n; i += stride)
        p[i] = 0u;
}

__device__ __forceinline__ ushort_t f2bf(float x) {
    union { float f; unsigned int u; } v; v.f = x;
    unsigned int r = v.u + 0x7FFFu + ((v.u >> 16) & 1u);
    return (ushort_t)(r >> 16);
}

__device__ __forceinline__ float hsig(float z) {
    return fminf(1.0f, fmaxf(0.0f, fmaf(z, 0.2f, 0.5f)));
}

__device__ __forceinline__ float fast_tanh(float x) {
    float e = __expf(2.0f * x);
    return 1.0f - 2.0f * __builtin_amdgcn_rcpf(e + 1.0f);
}

// ---------------- Phase A: xw[t'][b*8+k][col] = bias + x@W (fp32, proven) ----------------
__global__ __launch_bounds__(256) void xw_gemm(const float* __restrict__ x,
                                               const float* __restrict__ W,
                                               const float* __restrict__ bias,
                                               float* __restrict__ xw, int t0) {
    __shared__ __align__(16) float At[16][132];
    __shared__ __align__(16) float Bt[16][132];

    const int k  = blockIdx.z;
    const int C0 = blockIdx.x * 128;
    const int R0 = blockIdx.y * 128;
    const int tid = threadIdx.x;
    const int tx = tid & 15, ty = tid >> 4;

    float acc[8][8];
#pragma unroll
    for (int i = 0; i < 8; i++)
#pragma unroll
        for (int j = 0; j < 8; j++) acc[i][j] = 0.0f;

    const int lakk = tid & 15, larl = tid >> 4;
    const int lbc  = tid & 127, lbk = tid >> 7;

    for (int kt = 0; kt < NI; kt += 16) {
#pragma unroll
        for (int ps = 0; ps < 8; ps++) {
            int rloc = larl + ps * 16;
            int r = R0 + rloc;
            int b = r & 15, tp = r >> 4;
            At[lakk][rloc] = x[(((size_t)b * Tt + (t0 + tp)) * Kk + k) * NI + kt + lakk];
        }
#pragma unroll
        for (int ps = 0; ps < 8; ps++) {
            int kkr = lbk + ps * 2;
            Bt[kkr][lbc] = W[((size_t)k * NI + kt + kkr) * G4 + C0 + lbc];
        }
        __syncthreads();
#pragma unroll
        for (int kk = 0; kk < 16; kk++) {
            const float4* Ar = (const float4*)&At[kk][ty * 8];
            const float4* Br = (const float4*)&Bt[kk][tx * 8];
            float4 a0 = Ar[0], a1 = Ar[1];
            float4 b0 = Br[0], b1 = Br[1];
            float a[8] = {a0.x, a0.y, a0.z, a0.w, a1.x, a1.y, a1.z, a1.w};
            float bb[8] = {b0.x, b0.y, b0.z, b0.w, b1.x, b1.y, b1.z, b1.w};
#pragma unroll
            for (int i = 0; i < 8; i++)
#pragma unroll
                for (int j = 0; j < 8; j++)
                    acc[i][j] = fmaf(a[i], bb[j], acc[i][j]);
        }
        __syncthreads();
    }
    float bv[8];
#pragma unroll
    for (int j = 0; j < 8; j++) bv[j] = bias[(size_t)k * G4 + C0 + tx * 8 + j];
#pragma unroll
    for (int i = 0; i < 8; i++) {
        int r = R0 + ty * 8 + i;
        int b = r & 15, tp = r >> 4;
        float* op = xw + ((size_t)tp * 128 + b * 8 + k) * G4 + C0 + tx * 8;
#pragma unroll
        for (int j = 0; j < 8; j++) op[j] = acc[i][j] + bv[j];
    }
}

// ---------------- Phase B: round-2 shape + cheap sync + vector scatter ----------------
// 32 wgs x 256 thr: k=bid&7 (same-XCD peers), uq=bid>>3 owns units [uq*64,uq*64+64).
// wave w = gate w. bfr: 128 VGPR/lane of U slice. Flags: t-indexed, store/poll (no RMW).
__global__ __launch_bounds__(256, 1) void lstm_mfma3(
    const float* __restrict__ xw,        // [TC][128][1024]
    const float* __restrict__ U,
    float* __restrict__ out,
    ushort_t* __restrict__ hstate,       // [8][16][256] bf16
    float* __restrict__ cstate,          // [32][1024]
    ushort_t* __restrict__ hbuf,         // [2][8][16][256] bf16
    int* __restrict__ arrive,            // [(t*8+k)*4 + uq]
    int t0, int TC) {
    const int tid  = threadIdx.x;
    const int lane = tid & 63;
    const int w    = tid >> 6;        // gate
    const int k    = blockIdx.x & 7;
    const int uq   = blockIdx.x >> 3; // 0..3
    const int l15  = lane & 15, quad = lane >> 4;
    const int colw = w * 256 + uq * 64;

    __shared__ __align__(16) ushort_t hfr[8 * 64 * 8];   // A-frag layout, 8KB
    __shared__ float gact[4][16][65];

    // preload B-fragments of U slice (bf16): 128 VGPRs/lane
    short8 bfr[4][8];
    const size_t Ub = (size_t)k * (NI * G4);
#pragma unroll
    for (int c = 0; c < 4; c++) {
        const int col = colw + c * 16 + l15;
#pragma unroll
        for (int q = 0; q < 8; q++) {
            short8 v;
#pragma unroll
            for (int j = 0; j < 8; j++)
                v[j] = (short)f2bf(U[Ub + (size_t)(q * 32 + quad * 8 + j) * G4 + col]);
            bfr[c][q] = v;
        }
    }

    // c-state: thread owns (b = bq*4+r, unit = uq*64+uu)
    const int uu = tid & 63;
    const int bq = tid >> 6;
    float cc[4];
    const size_t cb = ((size_t)(k * 4 + uq)) * 1024 + (size_t)tid * 4;
#pragma unroll
    for (int r = 0; r < 4; r++) cc[r] = cstate[cb + r];

    // initial h scatter: hstate[k][b][unit] -> A-frag LDS (16B load + b128 write)
#pragma unroll
    for (int i = 0; i < 2; i++) {
        int idx = tid + 256 * i;
        int b = idx & 15, c8 = idx >> 4;      // c8 0..31
        short8 hv = *(const short8*)&hstate[(size_t)k * 4096 + b * 256 + c8 * 8];
        *(short8*)&hfr[(((c8 >> 2) * 64) + b + 16 * (c8 & 3)) * 8] = hv;
    }
    __syncthreads();

    // xw for t=0
    float xwv[4][4];
#pragma unroll
    for (int c = 0; c < 4; c++)
#pragma unroll
        for (int r = 0; r < 4; r++)
            xwv[c][r] = xw[((size_t)0 * 128 + (quad * 4 + r) * 8 + k) * G4 + colw + c * 16 + l15];

#pragma unroll 1
    for (int t = 0; t < TC; t++) {
        const int g = t0 + t;

        // prefetch xw for t+1 at loop top (max latency cover)
        float xwn[4][4];
        if (t + 1 < TC) {
#pragma unroll
            for (int c = 0; c < 4; c++)
#pragma unroll
                for (int r = 0; r < 4; r++)
                    xwn[c][r] = xw[((size_t)(t + 1) * 128 + (quad * 4 + r) * 8 + k) * G4 + colw + c * 16 + l15];
        }

        // z_hU = h @ Uslice via MFMA
        f32x4 acc[4];
        const f32x4 zv = {0.f, 0.f, 0.f, 0.f};
#pragma unroll
        for (int c = 0; c < 4; c++) acc[c] = zv;
#pragma unroll
        for (int q = 0; q < 8; q++) {
            short8 af = *(const short8*)&hfr[(q * 64 + lane) * 8];
#pragma unroll
            for (int c = 0; c < 4; c++)
                acc[c] = __builtin_amdgcn_mfma_f32_16x16x32_bf16(af, bfr[c][q], acc[c], 0, 0, 0);
        }

        // gate activation (wave w = gate w) -> LDS
#pragma unroll
        for (int c = 0; c < 4; c++)
#pragma unroll
            for (int r = 0; r < 4; r++) {
                float z = acc[c][r] + xwv[c][r];
                float a = (w == 0) ? fast_tanh(z) : hsig(z);
                gact[w][quad * 4 + r][c * 16 + l15] = a;
            }
        __syncthreads();   // S1: gact visible, hfr reads done

        // c/h update
        float hn[4];
#pragma unroll
        for (int r = 0; r < 4; r++) {
            int b = bq * 4 + r;
            float av = gact[0][b][uu], iv = gact[1][b][uu];
            float fv = gact[2][b][uu], ov = gact[3][b][uu];
            float cn = av * iv + fv * cc[r];
            cc[r] = cn;
            hn[r] = ov * fast_tanh(cn);
        }

        if (t + 1 < TC) {
            const int par = (g + 1) & 1;
            ushort_t* hb = hbuf + ((size_t)par * 8 + k) * 4096;
#pragma unroll
            for (int r = 0; r < 4; r++)
                hb[(bq * 4 + r) * 256 + uq * 64 + uu] = f2bf(hn[r]);
            __syncthreads();   // S2: drains hbuf stores wg-wide
            int* fl = arrive + ((size_t)(g + 1) * 8 + k) * 4;
            if (tid == 0)
                __hip_atomic_store(fl + uq, 1, __ATOMIC_RELEASE, __HIP_MEMORY_SCOPE_AGENT);
            // out stores here: drain overlaps the peer wait
#pragma unroll
            for (int r = 0; r < 4; r++)
                out[(((size_t)(bq * 4 + r) * Tt + g) * Kk + k) * UN + uq * 64 + uu] = hn[r];
            if (tid == 0) {
                for (;;) {
                    int a0 = __hip_atomic_load(fl + 0, __ATOMIC_ACQUIRE, __HIP_MEMORY_SCOPE_AGENT);
                    int a1 = __hip_atomic_load(fl + 1, __ATOMIC_ACQUIRE, __HIP_MEMORY_SCOPE_AGENT);
                    int a2 = __hip_atomic_load(fl + 2, __ATOMIC_ACQUIRE, __HIP_MEMORY_SCOPE_AGENT);
                    int a3 = __hip_atomic_load(fl + 3, __ATOMIC_ACQUIRE, __HIP_MEMORY_SCOPE_AGENT);
                    if (a0 & a1 & a2 & a3) break;
                }
            }
            __syncthreads();   // S3: all threads released
            // scatter full h_{t+1}: 16B loads + conflict-free ds_write_b128
            const ushort_t* src = hbuf + ((size_t)par * 8 + k) * 4096;
#pragma unroll
            for (int i = 0; i < 2; i++) {
                int idx = tid + 256 * i;
                int b = idx & 15, c8 = idx >> 4;
                short8 hv = *(const short8*)&src[b * 256 + c8 * 8];
                *(short8*)&hfr[(((c8 >> 2) * 64) + b + 16 * (c8 & 3)) * 8] = hv;
            }
            __syncthreads();   // S4: hfr ready
#pragma unroll
            for (int c = 0; c < 4; c++)
#pragma unroll
                for (int r = 0; r < 4; r++) xwv[c][r] = xwn[c][r];
        } else {
#pragma unroll
            for (int r = 0; r < 4; r++)
                out[(((size_t)(bq * 4 + r) * Tt + g) * Kk + k) * UN + uq * 64 + uu] = hn[r];
#pragma unroll
            for (int r = 0; r < 4; r++)
                hstate[(size_t)k * 4096 + (bq * 4 + r) * 256 + uq * 64 + uu] = f2bf(hn[r]);
#pragma unroll
            for (int r = 0; r < 4; r++) cstate[cb + r] = cc[r];
        }
    }
}

extern "C" void kernel_launch(void* const* d_in, const int* in_sizes, int n_in,
                              void* d_out, int out_size, void* d_ws, size_t ws_size,
                              hipStream_t stream) {
    const float* x    = (const float*)d_in[0];
    const float* W    = (const float*)d_in[1];
    const float* U    = (const float*)d_in[2];
    const float* bias = (const float*)d_in[3];
    float* out = (float*)d_out;

    // tail: cstate 128KB | hstate 64KB | hbuf 128KB | arrive 64KB
    const size_t TAIL = 131072 + 65536 + 131072 + 65536;  // 393216 B
    int TC = 16;
    const int cands[6] = {512, 256, 128, 64, 32, 16};
    for (int ci = 0; ci < 6; ci++) {
        size_t need = (size_t)cands[ci] * 128 * 1024 * 4 + TAIL;
        if (need <= ws_size) { TC = cands[ci]; break; }
    }

    float* xw = (float*)d_ws;
    char* p = (char*)d_ws + (size_t)TC * 128 * 1024 * 4;
    float*    cstate = (float*)p;     p += 131072;
    ushort_t* hstate = (ushort_t*)p;  p += 65536;
    ushort_t* hbuf   = (ushort_t*)p;  p += 131072;
    int*      arrive = (int*)p;

    zero_ws<<<dim3(128), dim3(256), 0, stream>>>((unsigned int*)cstate, (int)(TAIL / 4));

    for (int t0 = 0; t0 < Tt; t0 += TC) {
        xw_gemm<<<dim3(G4 / 128, TC * 16 / 128, Kk), dim3(256), 0, stream>>>(
            x, W, bias, xw, t0);
        lstm_mfma3<<<dim3(32), dim3(256), 0, stream>>>(
            xw, U, out, hstate, cstate, hbuf, arrive, t0, TC);
    }
}